// Round 10
// baseline (1125.772 us; speedup 1.0000x reference)
//
#include <hip/hip_runtime.h>
#include <hip/hip_bf16.h>
#include <math.h>

#define BB 32
#define QQ 900
#define NMM 300
#define DD 256
#define CCC 90
#define NCC 91
#define KB 5
#define MK 5

__device__ __forceinline__ float wsumf(float v){
#pragma unroll
  for(int o=32;o>0;o>>=1) v += __shfl_xor(v,o,64);
  return v;
}
__device__ __forceinline__ int wsumi(int v){
#pragma unroll
  for(int o=32;o>0;o>>=1) v += __shfl_xor(v,o,64);
  return v;
}
__device__ __forceinline__ void wargmax(float& v,int& i){
#pragma unroll
  for(int o=32;o>0;o>>=1){
    float v2=__shfl_xor(v,o,64); int i2=__shfl_xor(i,o,64);
    if(v2>v || (v2==v && i2<i)){v=v2;i=i2;}
  }
}

// zero ism+acc, write f32 canary {1,1} to out (overwritten by asgs_fin)
__global__ void asgs_zero(int* ism, float* acc, float* out){
  int i=blockIdx.x*blockDim.x+threadIdx.x;
  if(i<BB*QQ) ism[i]=0;
  if(i<64) acc[i]=0.f;
  if(i<2) out[i]=1.0f;
}

// fused prep: [0,2400) matched | [2400,9600) obj-norm | [9600,9623) proto | [9623,9647) WT4
#define PREP_M (BB*NMM/4)
#define PREP_O (BB*QQ/4)
#define PREP_P 23
#define PREP_W 24
__global__ __launch_bounds__(256) void asgs_prep(const float* __restrict__ obj,const int* __restrict__ src,
    const float* __restrict__ pr,const float* __restrict__ W,
    float* __restrict__ matched,float* __restrict__ invf,float* __restrict__ invs,int* __restrict__ ism,
    float* __restrict__ oinv,float* __restrict__ pscale,float4* __restrict__ WT4){
  int blk=blockIdx.x;
  if(blk<PREP_M){
    int wid=(blk*256+threadIdx.x)>>6, lane=threadIdx.x&63;
    int b=wid/NMM, n=wid-b*NMM;
    int q=src[b*NMM+n];
    float4 v=*(const float4*)(obj+((size_t)(b*QQ+q))*DD+lane*4);
    *(float4*)(matched+(size_t)wid*DD+lane*4)=v;
    float ss=wsumf(v.x*v.x+v.y*v.y+v.z*v.z+v.w*v.w);
    if(lane==0){
      float nr=sqrtf(ss);
      invf[wid]=1.f/fmaxf(nr,1e-12f);
      invs[wid]=1.f/fmaxf(nr,1e-6f);
      ism[b*QQ+q]=1;
    }
  }else if(blk<PREP_M+PREP_O){
    int wid=((blk-PREP_M)*256+threadIdx.x)>>6, lane=threadIdx.x&63;
    float4 v=*(const float4*)(obj+(size_t)wid*DD+lane*4);
    float ss=wsumf(v.x*v.x+v.y*v.y+v.z*v.z+v.w*v.w);
    if(lane==0) oinv[wid]=1.f/fmaxf(sqrtf(ss),1e-12f);
  }else if(blk<PREP_M+PREP_O+PREP_P){
    int wid=((blk-PREP_M-PREP_O)*256+threadIdx.x)>>6, lane=threadIdx.x&63;
    if(wid<CCC){
      float4 v=*(const float4*)(pr+(size_t)wid*DD+lane*4);
      float ss=wsumf(v.x*v.x+v.y*v.y+v.z*v.z+v.w*v.w);
      if(lane==0) pscale[wid]=1.f/fmaxf(sqrtf(ss),1e-6f);
    }
  }else{
    int i=(blk-PREP_M-PREP_O-PREP_P)*256+threadIdx.x;   // over 64*96
    if(i<64*96){
      int d4=i/96, c=i-d4*96;
      float4 v; v.x=0.f;v.y=0.f;v.z=0.f;v.w=0.f;
      if(c<NCC) v=*(const float4*)(W+(size_t)c*DD+d4*4);
      WT4[i]=v;
    }
  }
}

// one dot per (matched-row, class) serves sims (fnorm) and S (safe_norm*pscale/tau) + S^T
__global__ void asgs_simsS(const float* __restrict__ matched,const float* __restrict__ pr,
    const float* __restrict__ invf,const float* __restrict__ invs,const float* __restrict__ pscale,
    float* __restrict__ sims,float* __restrict__ S,float* __restrict__ ST){
  int wid=(blockIdx.x*blockDim.x+threadIdx.x)>>6, lane=threadIdx.x&63;
  if(wid>=BB*NMM) return;
  float4 m=*(const float4*)(matched+(size_t)wid*DD+lane*4);
  float fi=invf[wid], si=invs[wid];
  for(int c=0;c<CCC;c++){
    float4 p=*(const float4*)(pr+(size_t)c*DD+lane*4);
    float d=wsumf(m.x*p.x+m.y*p.y+m.z*p.z+m.w*p.w);
    if(lane==0){
      sims[(size_t)wid*CCC+c]=d*fi;
      float s=d*si*pscale[c]*10.0f;   // /TAU, TAU=0.1
      S[(size_t)wid*CCC+c]=s;
      ST[(size_t)c*(BB*NMM)+wid]=s;
    }
  }
}

// per (b,c): member count + top-K_B by dist desc (tie -> lower n)
__global__ void asgs_ctopk(const float* __restrict__ sims,const int* __restrict__ lab,
    int* __restrict__ cnt,int* __restrict__ topi){
  int wid=(blockIdx.x*blockDim.x+threadIdx.x)>>6, lane=threadIdx.x&63;
  if(wid>=BB*CCC) return;
  int b=wid/CCC, c=wid-b*CCC;
  float lv[KB]; int li[KB];
#pragma unroll
  for(int j=0;j<KB;j++){lv[j]=-3.4e38f;li[j]=1<<30;}
  int mc=0;
  for(int n=lane;n<NMM;n+=64){
    bool mem = lab[b*NMM+n]==c;
    float dd = mem ? (1.0f - sims[(size_t)(b*NMM+n)*CCC+c]) : -1.0e9f;
    if(mem) mc++;
    float cv=dd; int ci=n;
#pragma unroll
    for(int j=0;j<KB;j++){
      if(cv>lv[j] || (cv==lv[j] && ci<li[j])){
        float t1=lv[j]; int t2=li[j]; lv[j]=cv; li[j]=ci; cv=t1; ci=t2;
      }
    }
  }
  mc=wsumi(mc);
  for(int k=0;k<KB;k++){
    float v=lv[0]; int i=li[0];
#pragma unroll
    for(int j=1;j<KB;j++) if(lv[j]>v || (lv[j]==v && li[j]<i)){v=lv[j];i=li[j];}
    wargmax(v,i);
#pragma unroll
    for(int j=0;j<KB;j++) if(li[j]==i && lv[j]==v){lv[j]=-3.4e38f;li[j]=1<<30;}
    if(lane==0) topi[wid*KB+k]=(i<NMM)? i : 0;
  }
  if(lane==0) cnt[wid]=mc;
}

// v5: 2 waves/block, 8 q per lane, single d-pass. bn5 in LDS (broadcast),
// obj rows from global/L2. Candidates live in accumulators; per-wave top-5 by
// argmax-and-remove; 2-list cross-wave merge. XCD-swizzled block index.
__global__ __launch_bounds__(128) void asgs_simq(const float* __restrict__ obj,
    const float* __restrict__ matched,const float* __restrict__ invf,
    const float* __restrict__ oinv,const int* __restrict__ ism,
    const int* __restrict__ cnt,const int* __restrict__ topi,
    float* __restrict__ tops,int* __restrict__ topq){
  __shared__ float bn5[KB][DD];
  __shared__ float mtv[2][KB][MK];
  __shared__ int   mtq[2][KB][MK];
  int bcs=blockIdx.x;
  int bc=(bcs&7)*360+(bcs>>3);          // 2880 = 8*360, bijective
  int b=bc/CCC;
  int cc=cnt[bc];
  int t=threadIdx.x, wave=t>>6, lane=t&63;
  // stage scaled boundary rows: 320 float4 / 128 threads
#pragma unroll
  for(int it=0;it<3;++it){
    int idx=it*128+t;
    if(idx<320){
      int k=idx>>6, c4=idx&63;
      int nidx=topi[bc*KB+k];
      float sc=(k<cc)? invf[b*NMM+nidx] : 0.0f;
      float4 v=*(const float4*)(matched+((size_t)(b*NMM+nidx))*DD+c4*4);
      v.x*=sc; v.y*=sc; v.z*=sc; v.w*=sc;
      *(float4*)(&bn5[k][c4*4])=v;
    }
  }
  __syncthreads();

  const float* objb=obj+(size_t)b*QQ*DD;
  int   qv[8]; int rv[8];
#pragma unroll
  for(int j=0;j<8;++j){
    int q=(wave*8+j)*64+lane;
    qv[j]=q;
    rv[j]=(q<QQ)? q : 0;
  }
  float acc[KB][8];
#pragma unroll
  for(int k=0;k<KB;k++){
#pragma unroll
    for(int j=0;j<8;j++) acc[k][j]=0.f;
  }
#pragma unroll 2
  for(int d4=0;d4<64;++d4){
    float4 o0=*(const float4*)(objb+(size_t)rv[0]*DD+d4*4);
    float4 o1=*(const float4*)(objb+(size_t)rv[1]*DD+d4*4);
    float4 o2=*(const float4*)(objb+(size_t)rv[2]*DD+d4*4);
    float4 o3=*(const float4*)(objb+(size_t)rv[3]*DD+d4*4);
    float4 o4=*(const float4*)(objb+(size_t)rv[4]*DD+d4*4);
    float4 o5=*(const float4*)(objb+(size_t)rv[5]*DD+d4*4);
    float4 o6=*(const float4*)(objb+(size_t)rv[6]*DD+d4*4);
    float4 o7=*(const float4*)(objb+(size_t)rv[7]*DD+d4*4);
#pragma unroll
    for(int k=0;k<KB;k++){
      float4 bv=*(const float4*)(&bn5[k][d4*4]);
      acc[k][0]+=o0.x*bv.x+o0.y*bv.y+o0.z*bv.z+o0.w*bv.w;
      acc[k][1]+=o1.x*bv.x+o1.y*bv.y+o1.z*bv.z+o1.w*bv.w;
      acc[k][2]+=o2.x*bv.x+o2.y*bv.y+o2.z*bv.z+o2.w*bv.w;
      acc[k][3]+=o3.x*bv.x+o3.y*bv.y+o3.z*bv.z+o3.w*bv.w;
      acc[k][4]+=o4.x*bv.x+o4.y*bv.y+o4.z*bv.z+o4.w*bv.w;
      acc[k][5]+=o5.x*bv.x+o5.y*bv.y+o5.z*bv.z+o5.w*bv.w;
      acc[k][6]+=o6.x*bv.x+o6.y*bv.y+o6.z*bv.z+o6.w*bv.w;
      acc[k][7]+=o7.x*bv.x+o7.y*bv.y+o7.z*bv.z+o7.w*bv.w;
    }
  }
  float oi[8]; int mk[8];
#pragma unroll
  for(int j=0;j<8;++j){
    oi[j]=oinv[b*QQ+rv[j]];
    mk[j]=ism[b*QQ+rv[j]];
  }
  // per-wave top-5 per k: argmax-and-remove over the 8 lane candidates
#pragma unroll
  for(int k=0;k<KB;k++){
    float cv[8]; int cq[8];
#pragma unroll
    for(int j=0;j<8;++j){
      bool valid=qv[j]<QQ;
      cv[j]= valid ? ((mk[j]!=0)? -1.0e9f : acc[k][j]*oi[j]) : -3.4e38f;
      cq[j]= valid ? qv[j] : (1<<30);
    }
    for(int m=0;m<MK;m++){
      float v=cv[0]; int i=cq[0];
#pragma unroll
      for(int j=1;j<8;j++) if(cv[j]>v || (cv[j]==v && cq[j]<i)){v=cv[j];i=cq[j];}
      wargmax(v,i);
#pragma unroll
      for(int j=0;j<8;j++) if(cq[j]==i && cv[j]==v){cv[j]=-3.4e38f;cq[j]=1<<30;}
      if(lane==0){mtv[wave][k][m]=v;mtq[wave][k][m]=i;}
    }
  }
  __syncthreads();
  // cross-wave 2-list merge (lists are sorted desc with index tie-break)
  if(t<KB){
    int k=t, p0=0, p1=0;
    for(int m=0;m<MK;m++){
      float v0=mtv[0][k][p0]; int i0=mtq[0][k][p0];
      float v1=mtv[1][k][p1]; int i1=mtq[1][k][p1];
      bool take1=(v1>v0)||(v1==v0 && i1<i0);
      float v=take1?v1:v0; int i=take1?i1:i0;
      p0+=take1?0:1; p1+=take1?1:0;
      tops[((size_t)bc*KB+k)*MK+m]=v;
      topq[((size_t)bc*KB+k)*MK+m]=i;
    }
  }
}

// focal v2: g_bar -> LDS, lane = class, coalesced WT4 + broadcast LDS dot.
__global__ __launch_bounds__(64) void asgs_focal(const float* __restrict__ obj,
    const float* __restrict__ matched,const float4* __restrict__ WT4,const float* __restrict__ bcls,
    const int* __restrict__ cnt,const int* __restrict__ topi,
    const float* __restrict__ tops,const int* __restrict__ topq,float* __restrict__ acc){
  __shared__ float4 gb[64];
  int bcs=blockIdx.x;
  int bck=(bcs&7)*1800+(bcs>>3);        // 14400 = 8*1800, bijective
  int bc=bck/KB, k=bck-bc*KB;
  if(k>=cnt[bc]) return;
  int b=bc/CCC;
  int lane=threadIdx.x;
  int idx=topi[bck];
  float4 g=*(const float4*)(matched+((size_t)(b*NMM+idx))*DD+lane*4);
  float wsum=0.f; bool any=false;
#pragma unroll
  for(int m=0;m<MK;m++){
    float s=tops[(size_t)bck*MK+m];
    if(s>0.0f){                         // DELTA = 0, strict
      any=true; wsum+=1.0f;
      int q=topq[(size_t)bck*MK+m];
      float4 u=*(const float4*)(obj+((size_t)(b*QQ+q))*DD+lane*4);
      g.x+=u.x; g.y+=u.y; g.z+=u.z; g.w+=u.w;
    }
  }
  if(!any) return;
  float inv=1.0f/(1.0f+wsum);
  g.x*=inv; g.y*=inv; g.z*=inv; g.w*=inv;
  gb[lane]=g;
  __syncthreads();
  float fls=0.f;
#pragma unroll
  for(int h=0;h<2;h++){
    int c=lane+h*64;
    int cs=(c<NCC)? c : 0;
    float x=bcls[cs];
    float d=0.f;
#pragma unroll 4
    for(int d4=0;d4<64;++d4){
      float4 gv=gb[d4];
      float4 wv=WT4[d4*96+cs];
      d+=gv.x*wv.x+gv.y*wv.y+gv.z*wv.z+gv.w*wv.w;
    }
    x+=d;
    float sp=log1pf(expf(-fabsf(x)));
    float sig=1.0f/(1.0f+expf(-x));
    float fl;
    if(c==NCC-1){                       // t = 1
      float ce=fmaxf(-x,0.0f)+sp;
      float om=1.0f-sig;
      fl=0.25f*ce*om*om;
    }else{                              // t = 0
      float ce=fmaxf(x,0.0f)+sp;
      fl=0.75f*ce*sig*sig;
    }
    if(c<NCC) fls+=fl;
  }
  fls=wsumf(fls);
  if(lane==0){
    atomicAdd(&acc[0],fls*(1.0f/NCC));
    atomicAdd(&acc[1],1.0f);
  }
}

// per class c: lse over P column (diag masked) and S column (lab==c masked), logaddexp
__global__ __launch_bounds__(256) void asgs_lse(const float* __restrict__ pr,
    const float* __restrict__ pscale,const float* __restrict__ ST,
    const int* __restrict__ lab,float* __restrict__ lneg){
  int c=blockIdx.x, tid=threadIdx.x;
  __shared__ float pc[DD];
  __shared__ float pcol[CCC];
  __shared__ float red[256];
  pc[tid]=pr[(size_t)c*DD+tid];
  __syncthreads();
  if(tid<CCC){
    float d=0;
    for(int dd=0;dd<DD;dd++) d+=pr[(size_t)tid*DD+dd]*pc[dd];
    pcol[tid]=(tid==c)? -1.0e9f : d*pscale[tid]*pscale[c]*10.0f;
  }
  float mx=-3.4e38f;
  for(int i=tid;i<BB*NMM;i+=256){
    if(lab[i]!=c) mx=fmaxf(mx,ST[(size_t)c*(BB*NMM)+i]);
  }
  red[tid]=mx; __syncthreads();
  for(int s=128;s>0;s>>=1){ if(tid<s) red[tid]=fmaxf(red[tid],red[tid+s]); __syncthreads(); }
  float gmax=red[0]; __syncthreads();
  float sm=0;
  for(int i=tid;i<BB*NMM;i+=256){
    if(lab[i]!=c) sm+=expf(ST[(size_t)c*(BB*NMM)+i]-gmax);
  }
  red[tid]=sm; __syncthreads();
  for(int s=128;s>0;s>>=1){ if(tid<s) red[tid]+=red[tid+s]; __syncthreads(); }
  if(tid==0){
    float lseS=gmax+logf(red[0]);
    float pmx=-3.4e38f;
    for(int t2=0;t2<CCC;t2++) pmx=fmaxf(pmx,pcol[t2]);
    float ps=0;
    for(int t2=0;t2<CCC;t2++) ps+=expf(pcol[t2]-pmx);
    float lseP=pmx+logf(ps);
    float a=fmaxf(lseP,lseS);
    lneg[c]=a+log1pf(expf(-fabsf(lseP-lseS)));
  }
}

__global__ __launch_bounds__(256) void asgs_cec(const float* __restrict__ S,
    const int* __restrict__ lab,const float* __restrict__ lneg,float* __restrict__ acc){
  __shared__ float red[256];
  int tid=threadIdx.x;
  int i=blockIdx.x*256+tid;
  float v=0.f;
  if(i<BB*NMM){
    int l=lab[i];
    float pos=S[(size_t)i*CCC+l];
    float ln=lneg[l];
    float a=fmaxf(pos,ln);
    v=-pos + a + log1pf(expf(-fabsf(pos-ln)));
  }
  red[tid]=v; __syncthreads();
  for(int s=128;s>0;s>>=1){ if(tid<s) red[tid]+=red[tid+s]; __syncthreads(); }
  if(tid==0) atomicAdd(&acc[2],red[0]);
}

// f32 output — reference returns float32
__global__ void asgs_fin(const float* __restrict__ acc,float* __restrict__ out){
  if(threadIdx.x==0 && blockIdx.x==0){
    float sul=acc[0]/fmaxf(acc[1],1.0f);
    float cec=acc[2]/(float)(BB*NMM);
    out[0]=sul;
    out[1]=cec;
  }
}

extern "C" void kernel_launch(void* const* d_in,const int* in_sizes,int n_in,
                              void* d_out,int out_size,void* d_ws,size_t ws_size,
                              hipStream_t stream){
  (void)in_sizes;(void)n_in;(void)out_size;(void)ws_size;
  const float* obj=(const float*)d_in[0];
  const float* pr =(const float*)d_in[1];
  const float* W  =(const float*)d_in[2];
  const float* bcl=(const float*)d_in[3];
  const int* src  =(const int*)d_in[4];
  const int* lab  =(const int*)d_in[5];
  float* out=(float*)d_out;

  char* p=(char*)d_ws;
  auto take=[&](size_t n){ void* r=(void*)p; p+=(n+255)&~(size_t)255; return r; };
  float* matched=(float*)take((size_t)BB*NMM*DD*4);     // 9.83 MB
  float* sims  =(float*)take((size_t)BB*NMM*CCC*4);     // 3.46 MB
  float* S     =(float*)take((size_t)BB*NMM*CCC*4);     // 3.46 MB
  float* ST    =(float*)take((size_t)BB*NMM*CCC*4);     // 3.46 MB
  float* invf  =(float*)take((size_t)BB*NMM*4);
  float* invs  =(float*)take((size_t)BB*NMM*4);
  float* oinv  =(float*)take((size_t)BB*QQ*4);
  int*   ism   =(int*)  take((size_t)BB*QQ*4);
  float* pscale=(float*)take(128*4);
  float4* WT4  =(float4*)take((size_t)64*96*16);        // 96 KB
  int*   cnt   =(int*)  take((size_t)BB*CCC*4);
  int*   topi  =(int*)  take((size_t)BB*CCC*KB*4);
  float* tops  =(float*)take((size_t)BB*CCC*KB*MK*4);
  int*   topq  =(int*)  take((size_t)BB*CCC*KB*MK*4);
  float* lneg  =(float*)take(128*4);
  float* acc   =(float*)take(64*4);

  asgs_zero<<<(BB*QQ+255)/256,256,0,stream>>>(ism,acc,out);
  asgs_prep<<<PREP_M+PREP_O+PREP_P+PREP_W,256,0,stream>>>(obj,src,pr,W,matched,invf,invs,ism,oinv,pscale,WT4);
  asgs_simsS<<<BB*NMM/4,256,0,stream>>>(matched,pr,invf,invs,pscale,sims,S,ST);
  asgs_ctopk<<<BB*CCC/4,256,0,stream>>>(sims,lab,cnt,topi);
  asgs_simq<<<BB*CCC,128,0,stream>>>(obj,matched,invf,oinv,ism,cnt,topi,tops,topq);
  asgs_focal<<<BB*CCC*KB,64,0,stream>>>(obj,matched,WT4,bcl,cnt,topi,tops,topq,acc);
  asgs_lse<<<CCC,256,0,stream>>>(pr,pscale,ST,lab,lneg);
  asgs_cec<<<(BB*NMM+255)/256,256,0,stream>>>(S,lab,lneg,acc);
  asgs_fin<<<1,64,0,stream>>>(acc,out);
}

// Round 11
// 667.810 us; speedup vs baseline: 1.6858x; 1.6858x over previous
//
#include <hip/hip_runtime.h>
#include <hip/hip_bf16.h>
#include <math.h>

#define BB 32
#define QQ 900
#define QP 1024          // padded q stride
#define NMM 300
#define DD 256
#define CCC 90
#define NCC 91
#define KB 5
#define MK 5

__device__ __forceinline__ float wsumf(float v){
#pragma unroll
  for(int o=32;o>0;o>>=1) v += __shfl_xor(v,o,64);
  return v;
}
__device__ __forceinline__ int wsumi(int v){
#pragma unroll
  for(int o=32;o>0;o>>=1) v += __shfl_xor(v,o,64);
  return v;
}
__device__ __forceinline__ void wargmax(float& v,int& i){
#pragma unroll
  for(int o=32;o>0;o>>=1){
    float v2=__shfl_xor(v,o,64); int i2=__shfl_xor(i,o,64);
    if(v2>v || (v2==v && i2<i)){v=v2;i=i2;}
  }
}

// zero ism (padded 32x1024) + acc, f32 canary
__global__ void asgs_zero(int* ism, float* acc, float* out){
  int i=blockIdx.x*blockDim.x+threadIdx.x;
  if(i<BB*QP) ism[i]=0;
  if(i<64) acc[i]=0.f;
  if(i<2) out[i]=1.0f;
}

// fused prep: matched-norms/msrc | obj-norms | proto-norms | WT4 transpose
#define PREP_M (BB*NMM/4)
#define PREP_O (BB*QQ/4)
#define PREP_P 23
#define PREP_W 24
__global__ __launch_bounds__(256) void asgs_prep(const float* __restrict__ obj,const int* __restrict__ src,
    const float* __restrict__ pr,const float* __restrict__ W,
    int* __restrict__ msrc,float* __restrict__ invf,float* __restrict__ invs,int* __restrict__ ism,
    float* __restrict__ oinv,float* __restrict__ pscale,float4* __restrict__ WT4){
  int blk=blockIdx.x;
  if(blk<PREP_M){
    int wid=(blk*256+threadIdx.x)>>6, lane=threadIdx.x&63;
    int b=wid/NMM, n=wid-b*NMM;
    int q=src[b*NMM+n];
    float4 v=*(const float4*)(obj+((size_t)(b*QQ+q))*DD+lane*4);
    float ss=wsumf(v.x*v.x+v.y*v.y+v.z*v.z+v.w*v.w);
    if(lane==0){
      float nr=sqrtf(ss);
      invf[wid]=1.f/fmaxf(nr,1e-12f);
      invs[wid]=1.f/fmaxf(nr,1e-6f);
      msrc[wid]=b*QQ+q;
      ism[b*QP+q]=1;
    }
  }else if(blk<PREP_M+PREP_O){
    int wid=((blk-PREP_M)*256+threadIdx.x)>>6, lane=threadIdx.x&63;
    int b=wid/QQ, q=wid-b*QQ;
    float4 v=*(const float4*)(obj+(size_t)wid*DD+lane*4);
    float ss=wsumf(v.x*v.x+v.y*v.y+v.z*v.z+v.w*v.w);
    if(lane==0) oinv[b*QP+q]=1.f/fmaxf(sqrtf(ss),1e-12f);
  }else if(blk<PREP_M+PREP_O+PREP_P){
    int wid=((blk-PREP_M-PREP_O)*256+threadIdx.x)>>6, lane=threadIdx.x&63;
    if(wid<CCC){
      float4 v=*(const float4*)(pr+(size_t)wid*DD+lane*4);
      float ss=wsumf(v.x*v.x+v.y*v.y+v.z*v.z+v.w*v.w);
      if(lane==0) pscale[wid]=1.f/fmaxf(sqrtf(ss),1e-6f);
    }
  }else{
    int i=(blk-PREP_M-PREP_O-PREP_P)*256+threadIdx.x;   // over 64*96
    if(i<64*96){
      int d4=i/96, c=i-d4*96;
      float4 v; v.x=0.f;v.y=0.f;v.z=0.f;v.w=0.f;
      if(c<NCC) v=*(const float4*)(W+(size_t)c*DD+d4*4);
      WT4[i]=v;
    }
  }
}

// objT4[((b*64 + d4)*QP + q)] = float4 obj[b][q][d4*4..+3]  (LDS-tiled)
__global__ __launch_bounds__(256) void asgs_transpose(const float* __restrict__ obj,float* __restrict__ objT4f){
  __shared__ float tile[60][65];
  int qt=blockIdx.x, dt=blockIdx.y, b=blockIdx.z;
#pragma unroll
  for(int it=0;it<15;it++){
    int idx=it*256+threadIdx.x;
    int r=idx>>6, dc=idx&63;
    tile[r][dc]=obj[((size_t)(b*QQ+qt*60+r))*DD+dt*64+dc];
  }
  __syncthreads();
#pragma unroll
  for(int it=0;it<15;it++){
    int idx=it*256+threadIdx.x;
    int d4l=idx/240; int rem=idx-d4l*240; int ql=rem>>2, j=rem&3;
    objT4f[(((size_t)b*64+dt*16+d4l)*QP+qt*60+ql)*4+j]=tile[ql][d4l*4+j];
  }
}

// one dot per (matched-row, class): simsT (fnorm) and ST (safe_norm*pscale/tau), both [c][B*Nm]
__global__ void asgs_simsS(const float* __restrict__ obj,const int* __restrict__ msrc,
    const float* __restrict__ pr,
    const float* __restrict__ invf,const float* __restrict__ invs,const float* __restrict__ pscale,
    float* __restrict__ simsT,float* __restrict__ ST){
  int wid=(blockIdx.x*blockDim.x+threadIdx.x)>>6, lane=threadIdx.x&63;
  if(wid>=BB*NMM) return;
  float4 m=*(const float4*)(obj+(size_t)msrc[wid]*DD+lane*4);
  float fi=invf[wid], si=invs[wid];
  for(int c=0;c<CCC;c++){
    float4 p=*(const float4*)(pr+(size_t)c*DD+lane*4);
    float d=wsumf(m.x*p.x+m.y*p.y+m.z*p.z+m.w*p.w);
    if(lane==0){
      simsT[(size_t)c*(BB*NMM)+wid]=d*fi;
      ST[(size_t)c*(BB*NMM)+wid]=d*si*pscale[c]*10.0f;   // /TAU
    }
  }
}

// per (b,c): member count + top-K_B by dist desc (tie -> lower n); contiguous simsT reads
__global__ void asgs_ctopk(const float* __restrict__ simsT,const int* __restrict__ lab,
    int* __restrict__ cnt,int* __restrict__ topi){
  int wid=(blockIdx.x*blockDim.x+threadIdx.x)>>6, lane=threadIdx.x&63;
  if(wid>=BB*CCC) return;
  int b=wid/CCC, c=wid-b*CCC;
  const float* srow=simsT+(size_t)c*(BB*NMM)+b*NMM;
  float lv[KB]; int li[KB];
#pragma unroll
  for(int j=0;j<KB;j++){lv[j]=-3.4e38f;li[j]=1<<30;}
  int mc=0;
  for(int n=lane;n<NMM;n+=64){
    bool mem = lab[b*NMM+n]==c;
    float dd = mem ? (1.0f - srow[n]) : -1.0e9f;
    if(mem) mc++;
    float cv=dd; int ci=n;
#pragma unroll
    for(int j=0;j<KB;j++){
      if(cv>lv[j] || (cv==lv[j] && ci<li[j])){
        float t1=lv[j]; int t2=li[j]; lv[j]=cv; li[j]=ci; cv=t1; ci=t2;
      }
    }
  }
  mc=wsumi(mc);
  for(int k=0;k<KB;k++){
    float v=lv[0]; int i=li[0];
#pragma unroll
    for(int j=1;j<KB;j++) if(lv[j]>v || (lv[j]==v && li[j]<i)){v=lv[j];i=li[j];}
    wargmax(v,i);
#pragma unroll
    for(int j=0;j<KB;j++) if(li[j]==i && lv[j]==v){lv[j]=-3.4e38f;li[j]=1<<30;}
    if(lane==0) topi[wid*KB+k]=(i<NMM)? i : 0;
  }
  if(lane==0) cnt[wid]=mc;
}

// v6: block = (b, c-pair). 10 boundary rows in LDS (broadcast). COALESCED obj
// reads via objT4 (lane -> consecutive q). 4 waves x 4 q/lane. acc[10][4].
__global__ __launch_bounds__(256) void asgs_simq(const float4* __restrict__ objT4,
    const float* __restrict__ obj,const int* __restrict__ msrc,const float* __restrict__ invf,
    const float* __restrict__ oinv,const int* __restrict__ ism,
    const int* __restrict__ cnt,const int* __restrict__ topi,
    float* __restrict__ tops,int* __restrict__ topq){
  __shared__ float bn[2*KB][DD];
  __shared__ float mtv[4][2*KB][MK];
  __shared__ int   mtq[4][2*KB][MK];
  int bcs=blockIdx.x;
  int bp=(bcs&7)*180+(bcs>>3);          // 1440 = 8*180, bijective
  int b=bp/45, cp=bp-b*45;
  int c0=cp*2;
  int t=threadIdx.x, wave=t>>6, lane=t&63;
  // stage 10 scaled boundary rows: 640 float4 / 256 thr
#pragma unroll
  for(int it=0;it<3;++it){
    int idx=it*256+t;
    if(idx<640){
      int kk=idx>>6, c4=idx&63;
      int c=c0+(kk>=KB), k=kk-KB*(kk>=KB);
      int bcc=b*CCC+c;
      int nidx=topi[bcc*KB+k];
      float sc=(k<cnt[bcc])? invf[b*NMM+nidx] : 0.0f;
      float4 v=*(const float4*)(obj+(size_t)msrc[b*NMM+nidx]*DD+c4*4);
      v.x*=sc; v.y*=sc; v.z*=sc; v.w*=sc;
      *(float4*)(&bn[kk][c4*4])=v;
    }
  }
  __syncthreads();

  const float4* obT=objT4+(size_t)b*64*QP;
  float acc[2*KB][4];
#pragma unroll
  for(int kk=0;kk<2*KB;kk++){
#pragma unroll
    for(int j=0;j<4;j++) acc[kk][j]=0.f;
  }
#pragma unroll 2
  for(int d4=0;d4<64;++d4){
    float4 o0=obT[(size_t)d4*QP + wave*256 +   0 + lane];
    float4 o1=obT[(size_t)d4*QP + wave*256 +  64 + lane];
    float4 o2=obT[(size_t)d4*QP + wave*256 + 128 + lane];
    float4 o3=obT[(size_t)d4*QP + wave*256 + 192 + lane];
#pragma unroll
    for(int kk=0;kk<2*KB;kk++){
      float4 bv=*(const float4*)(&bn[kk][d4*4]);
      acc[kk][0]+=o0.x*bv.x+o0.y*bv.y+o0.z*bv.z+o0.w*bv.w;
      acc[kk][1]+=o1.x*bv.x+o1.y*bv.y+o1.z*bv.z+o1.w*bv.w;
      acc[kk][2]+=o2.x*bv.x+o2.y*bv.y+o2.z*bv.z+o2.w*bv.w;
      acc[kk][3]+=o3.x*bv.x+o3.y*bv.y+o3.z*bv.z+o3.w*bv.w;
    }
  }
  int   qj[4]; float oi[4]; int mk[4]; bool vj[4];
#pragma unroll
  for(int j=0;j<4;++j){
    int q=wave*256+j*64+lane;
    qj[j]=q; vj[j]=q<QQ;
    oi[j]=oinv[b*QP+q];      // padded arrays: q<1024 safe, invalid masked
    mk[j]=ism[b*QP+q];
  }
  // per-wave top-5 per kk over the 4 lane candidates
#pragma unroll
  for(int kk=0;kk<2*KB;kk++){
    float cv[4]; int cq[4];
#pragma unroll
    for(int j=0;j<4;++j){
      cv[j]= vj[j] ? ((mk[j]!=0)? -1.0e9f : acc[kk][j]*oi[j]) : -3.4e38f;
      cq[j]= vj[j] ? qj[j] : (1<<30);
    }
    for(int m=0;m<MK;m++){
      float v=cv[0]; int i=cq[0];
      if(cv[1]>v||(cv[1]==v&&cq[1]<i)){v=cv[1];i=cq[1];}
      if(cv[2]>v||(cv[2]==v&&cq[2]<i)){v=cv[2];i=cq[2];}
      if(cv[3]>v||(cv[3]==v&&cq[3]<i)){v=cv[3];i=cq[3];}
      wargmax(v,i);
#pragma unroll
      for(int j=0;j<4;j++) if(cq[j]==i && cv[j]==v){cv[j]=-3.4e38f;cq[j]=1<<30;}
      if(lane==0){mtv[wave][kk][m]=v;mtq[wave][kk][m]=i;}
    }
  }
  __syncthreads();
  // cross-wave 4-list merge per kk (lists sorted desc, index tie asc)
  if(t<2*KB){
    int kk=t;
    int c=c0+(kk>=KB), k=kk-KB*(kk>=KB);
    int bcc=b*CCC+c;
    int p0=0,p1=0,p2=0,p3=0;
    for(int m=0;m<MK;m++){
      float bv=mtv[0][kk][p0]; int bq=mtq[0][kk][p0]; int bw=0;
      if(mtv[1][kk][p1]>bv || (mtv[1][kk][p1]==bv && mtq[1][kk][p1]<bq)){bv=mtv[1][kk][p1];bq=mtq[1][kk][p1];bw=1;}
      if(mtv[2][kk][p2]>bv || (mtv[2][kk][p2]==bv && mtq[2][kk][p2]<bq)){bv=mtv[2][kk][p2];bq=mtq[2][kk][p2];bw=2;}
      if(mtv[3][kk][p3]>bv || (mtv[3][kk][p3]==bv && mtq[3][kk][p3]<bq)){bv=mtv[3][kk][p3];bq=mtq[3][kk][p3];bw=3;}
      p0+=(bw==0);p1+=(bw==1);p2+=(bw==2);p3+=(bw==3);
      tops[((size_t)bcc*KB+k)*MK+m]=bv;
      topq[((size_t)bcc*KB+k)*MK+m]=bq;
    }
  }
}

// focal: g_bar -> LDS, lane = class, coalesced WT4 + broadcast LDS dot.
__global__ __launch_bounds__(64) void asgs_focal(const float* __restrict__ obj,
    const int* __restrict__ msrc,const float4* __restrict__ WT4,const float* __restrict__ bcls,
    const int* __restrict__ cnt,const int* __restrict__ topi,
    const float* __restrict__ tops,const int* __restrict__ topq,float* __restrict__ acc){
  __shared__ float4 gb[64];
  int bcs=blockIdx.x;
  int bck=(bcs&7)*1800+(bcs>>3);        // 14400 = 8*1800, bijective
  int bc=bck/KB, k=bck-bc*KB;
  if(k>=cnt[bc]) return;
  int b=bc/CCC;
  int lane=threadIdx.x;
  int idx=topi[bck];
  float4 g=*(const float4*)(obj+(size_t)msrc[b*NMM+idx]*DD+lane*4);
  float wsum=0.f; bool any=false;
#pragma unroll
  for(int m=0;m<MK;m++){
    float s=tops[(size_t)bck*MK+m];
    if(s>0.0f){                         // DELTA = 0, strict
      any=true; wsum+=1.0f;
      int q=topq[(size_t)bck*MK+m];
      float4 u=*(const float4*)(obj+((size_t)(b*QQ+q))*DD+lane*4);
      g.x+=u.x; g.y+=u.y; g.z+=u.z; g.w+=u.w;
    }
  }
  if(!any) return;
  float inv=1.0f/(1.0f+wsum);
  g.x*=inv; g.y*=inv; g.z*=inv; g.w*=inv;
  gb[lane]=g;
  __syncthreads();
  float fls=0.f;
#pragma unroll
  for(int h=0;h<2;h++){
    int c=lane+h*64;
    int cs=(c<NCC)? c : 0;
    float x=bcls[cs];
    float d=0.f;
#pragma unroll 4
    for(int d4=0;d4<64;++d4){
      float4 gv=gb[d4];
      float4 wv=WT4[d4*96+cs];
      d+=gv.x*wv.x+gv.y*wv.y+gv.z*wv.z+gv.w*wv.w;
    }
    x+=d;
    float sp=log1pf(expf(-fabsf(x)));
    float sig=1.0f/(1.0f+expf(-x));
    float fl;
    if(c==NCC-1){                       // t = 1
      float ce=fmaxf(-x,0.0f)+sp;
      float om=1.0f-sig;
      fl=0.25f*ce*om*om;
    }else{                              // t = 0
      float ce=fmaxf(x,0.0f)+sp;
      fl=0.75f*ce*sig*sig;
    }
    if(c<NCC) fls+=fl;
  }
  fls=wsumf(fls);
  if(lane==0){
    atomicAdd(&acc[0],fls*(1.0f/NCC));
    atomicAdd(&acc[1],1.0f);
  }
}

// per class c: lse over P column (diag masked) and S column (lab==c masked), logaddexp
__global__ __launch_bounds__(256) void asgs_lse(const float* __restrict__ pr,
    const float* __restrict__ pscale,const float* __restrict__ ST,
    const int* __restrict__ lab,float* __restrict__ lneg){
  int c=blockIdx.x, tid=threadIdx.x;
  __shared__ float pc[DD];
  __shared__ float pcol[CCC];
  __shared__ float red[256];
  pc[tid]=pr[(size_t)c*DD+tid];
  __syncthreads();
  if(tid<CCC){
    float d=0;
    for(int dd=0;dd<DD;dd++) d+=pr[(size_t)tid*DD+dd]*pc[dd];
    pcol[tid]=(tid==c)? -1.0e9f : d*pscale[tid]*pscale[c]*10.0f;
  }
  float mx=-3.4e38f;
  for(int i=tid;i<BB*NMM;i+=256){
    if(lab[i]!=c) mx=fmaxf(mx,ST[(size_t)c*(BB*NMM)+i]);
  }
  red[tid]=mx; __syncthreads();
  for(int s=128;s>0;s>>=1){ if(tid<s) red[tid]=fmaxf(red[tid],red[tid+s]); __syncthreads(); }
  float gmax=red[0]; __syncthreads();
  float sm=0;
  for(int i=tid;i<BB*NMM;i+=256){
    if(lab[i]!=c) sm+=expf(ST[(size_t)c*(BB*NMM)+i]-gmax);
  }
  red[tid]=sm; __syncthreads();
  for(int s=128;s>0;s>>=1){ if(tid<s) red[tid]+=red[tid+s]; __syncthreads(); }
  if(tid==0){
    float lseS=gmax+logf(red[0]);
    float pmx=-3.4e38f;
    for(int t2=0;t2<CCC;t2++) pmx=fmaxf(pmx,pcol[t2]);
    float ps=0;
    for(int t2=0;t2<CCC;t2++) ps+=expf(pcol[t2]-pmx);
    float lseP=pmx+logf(ps);
    float a=fmaxf(lseP,lseS);
    lneg[c]=a+log1pf(expf(-fabsf(lseP-lseS)));
  }
}

__global__ __launch_bounds__(256) void asgs_cec(const float* __restrict__ ST,
    const int* __restrict__ lab,const float* __restrict__ lneg,float* __restrict__ acc){
  __shared__ float red[256];
  int tid=threadIdx.x;
  int i=blockIdx.x*256+tid;
  float v=0.f;
  if(i<BB*NMM){
    int l=lab[i];
    float pos=ST[(size_t)l*(BB*NMM)+i];
    float ln=lneg[l];
    float a=fmaxf(pos,ln);
    v=-pos + a + log1pf(expf(-fabsf(pos-ln)));
  }
  red[tid]=v; __syncthreads();
  for(int s=128;s>0;s>>=1){ if(tid<s) red[tid]+=red[tid+s]; __syncthreads(); }
  if(tid==0) atomicAdd(&acc[2],red[0]);
}

// f32 output — reference returns float32
__global__ void asgs_fin(const float* __restrict__ acc,float* __restrict__ out){
  if(threadIdx.x==0 && blockIdx.x==0){
    float sul=acc[0]/fmaxf(acc[1],1.0f);
    float cec=acc[2]/(float)(BB*NMM);
    out[0]=sul;
    out[1]=cec;
  }
}

extern "C" void kernel_launch(void* const* d_in,const int* in_sizes,int n_in,
                              void* d_out,int out_size,void* d_ws,size_t ws_size,
                              hipStream_t stream){
  (void)in_sizes;(void)n_in;(void)out_size;(void)ws_size;
  const float* obj=(const float*)d_in[0];
  const float* pr =(const float*)d_in[1];
  const float* W  =(const float*)d_in[2];
  const float* bcl=(const float*)d_in[3];
  const int* src  =(const int*)d_in[4];
  const int* lab  =(const int*)d_in[5];
  float* out=(float*)d_out;

  char* p=(char*)d_ws;
  auto take=[&](size_t n){ void* r=(void*)p; p+=(n+255)&~(size_t)255; return r; };
  float4* objT4=(float4*)take((size_t)BB*64*QP*16);     // 33.55 MB
  float* simsT =(float*)take((size_t)CCC*BB*NMM*4);     // 3.46 MB
  float* ST    =(float*)take((size_t)CCC*BB*NMM*4);     // 3.46 MB
  float* invf  =(float*)take((size_t)BB*NMM*4);
  float* invs  =(float*)take((size_t)BB*NMM*4);
  int*   msrc  =(int*)  take((size_t)BB*NMM*4);
  float* oinv  =(float*)take((size_t)BB*QP*4);
  int*   ism   =(int*)  take((size_t)BB*QP*4);
  float* pscale=(float*)take(128*4);
  float4* WT4  =(float4*)take((size_t)64*96*16);        // 96 KB
  int*   cnt   =(int*)  take((size_t)BB*CCC*4);
  int*   topi  =(int*)  take((size_t)BB*CCC*KB*4);
  float* tops  =(float*)take((size_t)BB*CCC*KB*MK*4);
  int*   topq  =(int*)  take((size_t)BB*CCC*KB*MK*4);
  float* lneg  =(float*)take(128*4);
  float* acc   =(float*)take(64*4);

  asgs_zero<<<(BB*QP+255)/256,256,0,stream>>>(ism,acc,out);
  asgs_prep<<<PREP_M+PREP_O+PREP_P+PREP_W,256,0,stream>>>(obj,src,pr,W,msrc,invf,invs,ism,oinv,pscale,WT4);
  asgs_transpose<<<dim3(15,4,BB),256,0,stream>>>(obj,(float*)objT4);
  asgs_simsS<<<BB*NMM/4,256,0,stream>>>(obj,msrc,pr,invf,invs,pscale,simsT,ST);
  asgs_ctopk<<<BB*CCC/4,256,0,stream>>>(simsT,lab,cnt,topi);
  asgs_simq<<<BB*CCC/2,256,0,stream>>>(objT4,obj,msrc,invf,oinv,ism,cnt,topi,tops,topq);
  asgs_focal<<<BB*CCC*KB,64,0,stream>>>(obj,msrc,WT4,bcl,cnt,topi,tops,topq,acc);
  asgs_lse<<<CCC,256,0,stream>>>(pr,pscale,ST,lab,lneg);
  asgs_cec<<<(BB*NMM+255)/256,256,0,stream>>>(ST,lab,lneg,acc);
  asgs_fin<<<1,64,0,stream>>>(acc,out);
}